// Round 7
// baseline (186.948 us; speedup 1.0000x reference)
//
#include <hip/hip_runtime.h>
#include <hip/hip_bf16.h>
#include <math.h>

#define Bsz 2
#define Tsz 2048
#define Csz 1024
#define Hsz 16
#define Dsz 64

typedef __attribute__((ext_vector_type(8))) short frag8;      // 8 bf16
typedef __attribute__((ext_vector_type(4))) float f4;         // MFMA C/D
typedef __attribute__((ext_vector_type(8))) unsigned short us8;
typedef __attribute__((ext_vector_type(4))) _Float16 frag4h;  // 4 f16
typedef __attribute__((ext_vector_type(8))) _Float16 frag8h;  // 8 f16

static __device__ __forceinline__ unsigned short f2bf(float f) {
  union { __hip_bfloat16 h; unsigned short u; } c;
  c.h = __float2bfloat16(f);
  return c.u;
}
static __device__ __forceinline__ unsigned short f2h(float f) {
  union { _Float16 h; unsigned short u; } c;
  c.h = (_Float16)f;
  return c.u;
}

#define GLDS16(g, l)                                                        \
  __builtin_amdgcn_global_load_lds(                                         \
      (const __attribute__((address_space(1))) void*)(g),                   \
      (__attribute__((address_space(3))) void*)(l), 16, 0, 0)

// Q pre-scale: 1/sqrt(64) * log2(e)  (exp2 in attention)
#define QSCALE 0.18033688f

// ---------------------------------------------------------------------------
// cast x fp32 -> bf16
// ---------------------------------------------------------------------------
__global__ __launch_bounds__(256) void cast_x(const float* __restrict__ x,
                                              unsigned short* __restrict__ xb) {
  const int i = (blockIdx.x * 256 + threadIdx.x) * 8;
  const float4 a = *(const float4*)(x + i);
  const float4 b = *(const float4*)(x + i + 4);
  us8 v;
  v[0] = f2bf(a.x); v[1] = f2bf(a.y); v[2] = f2bf(a.z); v[3] = f2bf(a.w);
  v[4] = f2bf(b.x); v[5] = f2bf(b.y); v[6] = f2bf(b.z); v[7] = f2bf(b.w);
  *(us8*)(xb + i) = v;
}

// ---------------------------------------------------------------------------
// Transpose-cast: 4x fp32 [1024][1024] -> bf16 transposed.
// ---------------------------------------------------------------------------
__global__ __launch_bounds__(256) void transpose_cast(
    const float* __restrict__ s0, const float* __restrict__ s1,
    const float* __restrict__ s2, const float* __restrict__ s3,
    unsigned short* __restrict__ d0, unsigned short* __restrict__ d1,
    unsigned short* __restrict__ d2, unsigned short* __restrict__ d3) {
  __shared__ float Ls[64][65];
  const int mat = blockIdx.x >> 8;
  const int tile = blockIdx.x & 255;
  const float* src = mat == 0 ? s0 : mat == 1 ? s1 : mat == 2 ? s2 : s3;
  unsigned short* dst = mat == 0 ? d0 : mat == 1 ? d1 : mat == 2 ? d2 : d3;
  const int tr0 = (tile >> 4) << 6, tc0 = (tile & 15) << 6;
  const int t = threadIdx.x;
  const int lr = t >> 4, lc = (t & 15) << 2;
#pragma unroll
  for (int j = 0; j < 4; ++j) {
    const float4 v = *(const float4*)(src + (size_t)(tr0 + lr + j * 16) * 1024 + tc0 + lc);
    Ls[lr + j * 16][lc + 0] = v.x;
    Ls[lr + j * 16][lc + 1] = v.y;
    Ls[lr + j * 16][lc + 2] = v.z;
    Ls[lr + j * 16][lc + 3] = v.w;
  }
  __syncthreads();
#pragma unroll
  for (int j = 0; j < 4; ++j) {
    ushort4 v;
    v.x = f2bf(Ls[lc + 0][lr + j * 16]);
    v.y = f2bf(Ls[lc + 1][lr + j * 16]);
    v.z = f2bf(Ls[lc + 2][lr + j * 16]);
    v.w = f2bf(Ls[lc + 3][lr + j * 16]);
    *(ushort4*)(dst + (size_t)(tc0 + lr + j * 16) * 1024 + tr0 + lc) = v;
  }
}

// ---------------------------------------------------------------------------
// bf16 MFMA GEMM: C[M][N] = A[M][K=1024] . Bt[N][K]^T.  BK=64, 128-col tile.
// MODE 0 (MT=4): fused QKV (N=3072): col<1024 -> Qb (*QSCALE) bf16 [B,H,T,D];
//     col<2048 -> Kb bf16 [B,H,T,D]; else -> VTb f16 [B,H,D,T'] key-swizzled.
// MODE 2 (MT=2): OUT: fp32 + bias, [M][1024]
// ---------------------------------------------------------------------------
template <int MODE, int MT>
__global__ __launch_bounds__(256) void mm_bt(
    const unsigned short* __restrict__ A, const unsigned short* __restrict__ Bt,
    const float* __restrict__ bias, unsigned short* __restrict__ O0,
    unsigned short* __restrict__ O1, unsigned short* __restrict__ O2,
    float* __restrict__ Of) {
  __shared__ __align__(16) unsigned short As[MT * 32 * 64];
  __shared__ __align__(16) unsigned short Bs[128 * 64];
  const int K = 1024;
  const int tid = threadIdx.x;
  const int wave = tid >> 6, lane = tid & 63;
  const int quad = lane >> 4, l16 = lane & 15;
  const int wrow = (wave >> 1) * (MT * 16), wn = wave & 1;
  const int row0 = blockIdx.y * (MT * 32), col0 = blockIdx.x << 7;

  const int sr = lane >> 3, sg = lane & 7;
  const int g0 = sg ^ sr;
  const unsigned short* gA = A + (size_t)(row0 + wave * (MT * 8) + sr) * K + (g0 << 3);
  const unsigned short* gB = Bt + (size_t)(col0 + wave * 32 + sr) * K + (g0 << 3);

  f4 acc[MT][4];
#pragma unroll
  for (int i = 0; i < MT; ++i)
#pragma unroll
    for (int j = 0; j < 4; ++j) acc[i][j] = (f4){0.f, 0.f, 0.f, 0.f};

  for (int kk = 0; kk < K; kk += 64) {
    __syncthreads();
#pragma unroll
    for (int s = 0; s < MT; ++s)
      GLDS16(gA + kk + (size_t)(s * 8) * K, &As[(wave * (MT * 8) + s * 8) * 64]);
#pragma unroll
    for (int s = 0; s < 4; ++s)
      GLDS16(gB + kk + (size_t)(s * 8) * K, &Bs[(wave * 32 + s * 8) * 64]);
    __syncthreads();

#pragma unroll
    for (int ks = 0; ks < 2; ++ks) {
      frag8 af[MT], bf[4];
#pragma unroll
      for (int mt = 0; mt < MT; ++mt) {
        const int r = wrow + mt * 16 + l16;
        af[mt] = *(const frag8*)&As[r * 64 + (((ks * 4 + quad) ^ (l16 & 7)) << 3)];
      }
#pragma unroll
      for (int nt = 0; nt < 4; ++nt) {
        const int n = wn * 64 + nt * 16 + l16;
        bf[nt] = *(const frag8*)&Bs[n * 64 + (((ks * 4 + quad) ^ (l16 & 7)) << 3)];
      }
#pragma unroll
      for (int mt = 0; mt < MT; ++mt)
#pragma unroll
        for (int nt = 0; nt < 4; ++nt)
          acc[mt][nt] = __builtin_amdgcn_mfma_f32_16x16x32_bf16(af[mt], bf[nt], acc[mt][nt], 0, 0, 0);
    }
  }

  // ---- epilogue. C/D: col = l16, row = quad*4 + reg.
  if (MODE == 0) {
    if (col0 < 2048) {
      const bool isK = (col0 >= 1024);
      unsigned short* dst = isK ? O1 : O0;
      const float sc = isK ? 1.0f : QSCALE;
#pragma unroll
      for (int mt = 0; mt < MT; ++mt)
#pragma unroll
        for (int nt = 0; nt < 4; ++nt) {
          const int m = row0 + wrow + mt * 16 + quad * 4;          // token
          const int n = (col0 & 1023) + wn * 64 + nt * 16 + l16;   // channel
          const int b = m >> 11, h = n >> 6, d = n & 63;
#pragma unroll
          for (int r = 0; r < 4; ++r) {
            const int tk = (m + r) & (Tsz - 1);
            dst[(((size_t)b * Hsz + h) * Tsz + tk) * Dsz + d] = f2bf(acc[mt][nt][r] * sc);
          }
        }
    } else {
      // V^T f16 [B,H,D,T'] key-swizzled; 4 consecutive tokens packed
#pragma unroll
      for (int mt = 0; mt < MT; ++mt)
#pragma unroll
        for (int nt = 0; nt < 4; ++nt) {
          const int tok = row0 + wrow + mt * 16 + quad * 4;
          const int ch = (col0 - 2048) + wn * 64 + nt * 16 + l16;
          const int b = tok >> 11, tk = tok & (Tsz - 1);
          const int h = ch >> 6, d = ch & 63;
          const int t5 = tk & 31;
          const int pos = (tk & ~31) + ((t5 >> 4) << 2) + (((t5 >> 2) & 3) << 3) + (t5 & 3);
          ushort4 v;
          v.x = f2h(acc[mt][nt][0]); v.y = f2h(acc[mt][nt][1]);
          v.z = f2h(acc[mt][nt][2]); v.w = f2h(acc[mt][nt][3]);
          *(ushort4*)&O2[(((size_t)b * Hsz + h) * Dsz + d) * Tsz + pos] = v;
        }
    }
  } else {
#pragma unroll
    for (int mt = 0; mt < MT; ++mt)
#pragma unroll
      for (int nt = 0; nt < 4; ++nt) {
        const int m = row0 + wrow + mt * 16 + quad * 4;
        const int n = col0 + wn * 64 + nt * 16 + l16;
        const float bv = bias[n];
#pragma unroll
        for (int r = 0; r < 4; ++r)
          Of[(size_t)(m + r) * Csz + n] = acc[mt][nt][r] + bv;
      }
  }
}

// ---------------------------------------------------------------------------
// MFMA flash attention v12: WAVE-PRIVATE LDS staging, barrier-free main loop.
// v11 post-mortem: SIMD rebalance = exactly baseline (47.5us) -> imbalance
// is BLOCK-level: per-iteration __syncthreads lockstep makes light-tile
// waves idle ~45% of all wave-iterations, and its implicit vmcnt(0) caps the
// staging pipeline. Both removed at once:
//  - each wave stages its OWN 32-key K/V chunk into its OWN LDS double
//    buffer via global_load_lds and consumes it ITSELF. Same-wave GLDS->
//    ds_read visibility needs only a counted s_waitcnt vmcnt(N) (m135
//    in-order retirement), NO barrier. Counted vmcnt(8) = next chunk's 8
//    loads stay in flight (T4). Prefetch i+2 issued mid-iteration after an
//    explicit lgkmcnt(0) frees the just-read buffer.
//  - one q-tile per 256-thr block, 4 waves = 4 key splits (c==sp mod 4):
//    every wave computes every iteration (tail imbalance <=1 chunk).
//    2048 blocks heavy-first (j=63 first) pack CUs fine-grained.
//  - LDS 4 waves x 2 bufs x 8KB = 64KB -> 2 blocks/CU, 8 waves/CU.
//  - combine: 2 barriers (writers must wait for staging readers of the
//    overlapping LDS region). Plain-exp partial linearity as before.
//  - P->f16 back to RNE scalar casts (cvt_pkrtz RTZ doubled absmax).
// ---------------------------------------------------------------------------
__global__ __launch_bounds__(256, 2) void attn_mfma(
    const unsigned short* __restrict__ Qb,   // bf16 [B,H,T,D], *QSCALE
    const unsigned short* __restrict__ Kb,   // bf16 [B,H,T,D]
    const unsigned short* __restrict__ VTb,  // f16  [B,H,D,T'] key-swizzled
    unsigned short* __restrict__ Y) {        // bf16 [B,T,C]
  // [wave][buf][ K: 2048 shorts | V: 2048 shorts ]  = 64 KB
  __shared__ __align__(16) unsigned short SM[4][2][4096];

  const int tid = threadIdx.x;
  const int sp = tid >> 6, lane = tid & 63;  // sp = key split 0..3
  const int quad = lane >> 4, l16 = lane & 15;

  const int bh = blockIdx.x & 31;            // head pinned to XCD (bh%8)
  const int j = 63 - (blockIdx.x >> 5);      // q-tile, heavy first
  const int qb0 = j << 5;

  const unsigned short* Qh = Qb + (size_t)bh * Tsz * Dsz;
  const unsigned short* Kh = Kb + (size_t)bh * Tsz * Dsz;
  const unsigned short* Vh = VTb + (size_t)bh * Dsz * Tsz;

  // staging source bases (per lane), swizzles match the LDS frag-read layout
  const int sr = lane >> 3, sg = lane & 7;
  const unsigned short* gK = Kh + (size_t)sr * Dsz + ((sg ^ sr) << 3);
  const int vr = lane >> 2, vc = lane & 3;
  const unsigned short* gV = Vh + (size_t)vr * Tsz + ((vc ^ ((vr + (vr >> 2)) & 3)) << 3);

  // Q frags: B-operand (col=q=l16, k=quad*8+jj over d)
  frag8 qf[2][2];
#pragma unroll
  for (int m = 0; m < 2; ++m)
#pragma unroll
    for (int ks = 0; ks < 2; ++ks)
      qf[m][ks] = *(const frag8*)(Qh + (size_t)(qb0 + m * 16 + l16) * Dsz + ks * 32 + quad * 8);
  // retire Q loads so vmcnt bookkeeping below counts only GLDS ops
  asm volatile("s_waitcnt vmcnt(0)" ::: "memory");

  f4 o[2][4];
  float lsum[2] = {0.f, 0.f};
#pragma unroll
  for (int m = 0; m < 2; ++m)
#pragma unroll
    for (int nt = 0; nt < 4; ++nt) o[m][nt] = (f4){0.f, 0.f, 0.f, 0.f};
  const f4 zf = (f4){0.f, 0.f, 0.f, 0.f};
  const int fl = (l16 + (l16 >> 2)) & 3;     // V read swizzle key

  const int nc = (j >= sp) ? ((j - sp) >> 2) + 1 : 0;

  // stage chunk cc (32 keys: 4KB K + 4KB V) into this wave's buffer bb.
  auto STAGE = [&](int bb, int cc) {
#pragma unroll
    for (int g = 0; g < 4; ++g)
      GLDS16(gK + (size_t)cc * 2048 + g * 512, &SM[sp][bb][g * 512]);
#pragma unroll
    for (int g = 0; g < 4; ++g)
      GLDS16(gV + (size_t)g * 16 * Tsz + cc * 32, &SM[sp][bb][2048 + g * 512]);
  };

  if (nc > 0) STAGE(0, sp);
  if (nc > 1) STAGE(1, sp + 4);

  for (int i = 0; i < nc; ++i) {
    const int c = sp + 4 * i;
    const int bsel = i & 1;
    // counted wait: chunk i landed; chunk i+1's 8 loads may stay in flight.
    if (i + 1 < nc) asm volatile("s_waitcnt vmcnt(8)" ::: "memory");
    else            asm volatile("s_waitcnt vmcnt(0)" ::: "memory");

    const unsigned short* Kl = &SM[sp][bsel][0];
    const unsigned short* Vl = &SM[sp][bsel][2048];
    frag8 kf[2][2];
#pragma unroll
    for (int n = 0; n < 2; ++n)
#pragma unroll
      for (int ks = 0; ks < 2; ++ks)
        kf[n][ks] = *(const frag8*)&Kl[(n * 16 + l16) * 64 + (((ks * 4 + quad) ^ (l16 & 7)) << 3)];
    frag8h vf[4];
#pragma unroll
    for (int nt = 0; nt < 4; ++nt)
      vf[nt] = *(const frag8h*)&Vl[(nt * 16 + l16) * 32 + ((quad ^ fl) << 3)];

    f4 st[2][2];
#pragma unroll
    for (int n = 0; n < 2; ++n)
#pragma unroll
      for (int m = 0; m < 2; ++m) {
        f4 a = __builtin_amdgcn_mfma_f32_16x16x32_bf16(kf[n][0], qf[m][0], zf, 0, 0, 0);
        st[n][m] = __builtin_amdgcn_mfma_f32_16x16x32_bf16(kf[n][1], qf[m][1], a, 0, 0, 0);
      }

    // prefetch chunk i+2 into the buffer just read (frags now in VGPRs).
    if (i + 2 < nc) {
      asm volatile("s_waitcnt lgkmcnt(0)" ::: "memory");  // ds_reads retired
      STAGE(bsel, c + 8);
    }

    const bool dm = (c == j);
    frag4h paf[2][2];
#pragma unroll
    for (int m = 0; m < 2; ++m) {
      const int qq = m * 16 + l16;
#pragma unroll
      for (int n = 0; n < 2; ++n) {
        const int key0 = n * 16 + quad * 4;
        float p[4];
#pragma unroll
        for (int r = 0; r < 4; ++r) {
          float sv = st[n][m][r];
          if (dm && (key0 + r > qq)) sv = -INFINITY;
          p[r] = __builtin_amdgcn_exp2f(sv);
        }
        lsum[m] += (p[0] + p[1]) + (p[2] + p[3]);
        frag4h ph;
        ph[0] = (_Float16)p[0]; ph[1] = (_Float16)p[1];
        ph[2] = (_Float16)p[2]; ph[3] = (_Float16)p[3];
        paf[m][n] = ph;
      }
    }
#pragma unroll
    for (int m = 0; m < 2; ++m)
#pragma unroll
      for (int nt = 0; nt < 4; ++nt) {
        const frag4h vlo = __builtin_shufflevector(vf[nt], vf[nt], 0, 1, 2, 3);
        const frag4h vhi = __builtin_shufflevector(vf[nt], vf[nt], 4, 5, 6, 7);
        f4 a = __builtin_amdgcn_mfma_f32_16x16x16f16(paf[m][0], vlo, o[m][nt], 0, 0, 0);
        o[m][nt] = __builtin_amdgcn_mfma_f32_16x16x16f16(paf[m][1], vhi, a, 0, 0, 0);
      }
  }

  // ---- combine partials across sp (plain-exp linearity).
  // Barrier 1: all waves done reading their staging LDS (comb overlaps it).
  __syncthreads();
  float* comb = (float*)SM;
  float* cp = comb + (size_t)((sp - 1) * 64 + lane) * 37;  // stride 37 coprime w/32
  if (sp != 0) {
#pragma unroll
    for (int m = 0; m < 2; ++m)
#pragma unroll
      for (int nt = 0; nt < 4; ++nt)
        *(f4*)(cp + m * 16 + nt * 4) = o[m][nt];
    cp[32] = lsum[0]; cp[33] = lsum[1];
  }
  __syncthreads();
  if (sp == 0) {
#pragma unroll
    for (int s = 0; s < 3; ++s) {
      const float* rp = comb + (size_t)(s * 64 + lane) * 37;
#pragma unroll
      for (int m = 0; m < 2; ++m)
#pragma unroll
        for (int nt = 0; nt < 4; ++nt)
          o[m][nt] += *(const f4*)(rp + m * 16 + nt * 4);
      lsum[0] += rp[32]; lsum[1] += rp[33];
    }

    // reduce per-q sums across quads, normalize, write out
#pragma unroll
    for (int m = 0; m < 2; ++m) {
      lsum[m] += __shfl_xor(lsum[m], 16);
      lsum[m] += __shfl_xor(lsum[m], 32);
    }
    const int b = bh >> 4, h = bh & 15;
#pragma unroll
    for (int m = 0; m < 2; ++m)
#pragma unroll
      for (int r = 0; r < 4; ++r) {
        const float inv = 1.f / __shfl(lsum[m], quad * 4 + r);
        const int tk = qb0 + m * 16 + quad * 4 + r;
        unsigned short* yp = Y + ((size_t)b * Tsz + tk) * Csz + h * 64 + l16;
#pragma unroll
        for (int nt = 0; nt < 4; ++nt)
          yp[nt * 16] = f2bf(o[m][nt][r] * inv);
      }
  }
}

// ---------------------------------------------------------------------------
extern "C" void kernel_launch(void* const* d_in, const int* in_sizes, int n_in,
                              void* d_out, int out_size, void* d_ws, size_t ws_size,
                              hipStream_t stream) {
  const float* x  = (const float*)d_in[0];
  const float* Wq = (const float*)d_in[1];
  const float* Wk = (const float*)d_in[2];
  const float* Wv = (const float*)d_in[3];
  const float* Wo = (const float*)d_in[4];
  const float* bo = (const float*)d_in[5];

  const size_t NEL = (size_t)Bsz * Tsz * Csz;     // 4M
  const size_t WSZ = (size_t)Csz * Csz;           // 1M
  unsigned short* xb  = (unsigned short*)d_ws;    // 8 MB
  unsigned short* WT  = xb + NEL;                 // 6 MB (Wq|Wk|Wv ^T)
  unsigned short* WoT = WT + 3 * WSZ;             // 2 MB
  unsigned short* Qb  = WoT + WSZ;                // 8 MB
  unsigned short* Kb  = Qb + NEL;                 // 8 MB
  unsigned short* VTb = Kb + NEL;                 // 8 MB (f16 bits, key-swizzled)
  unsigned short* Yb  = VTb + NEL;                // 8 MB

  cast_x<<<NEL / 2048, 256, 0, stream>>>(x, xb);
  transpose_cast<<<1024, 256, 0, stream>>>(Wq, Wk, Wv, Wo,
                                           WT, WT + WSZ, WT + 2 * WSZ, WoT);

  // fused QKV: C[4096][3072] = xb . WT^T   (128x128 tiles)
  mm_bt<0, 4><<<dim3(24, 32), 256, 0, stream>>>(xb, WT, nullptr, Qb, Kb, VTb, nullptr);

  attn_mfma<<<2048, 256, 0, stream>>>(Qb, Kb, VTb, Yb);

  // out: C[4096][1024] = Yb . WoT^T + b    (64x128 tiles -> 512 blocks)
  mm_bt<2, 2><<<dim3(8, 64), 256, 0, stream>>>(Yb, WoT, bo, nullptr, nullptr, nullptr,
                                               (float*)d_out);
}